// Round 7
// baseline (235.995 us; speedup 1.0000x reference)
//
#include <hip/hip_runtime.h>
#include <math.h>

typedef __bf16 bf16x8 __attribute__((ext_vector_type(8)));
typedef float f32x4 __attribute__((ext_vector_type(4)));
typedef float f32x2 __attribute__((ext_vector_type(2)));

#define NVIEWS 4
#define RESN 64
#define PP 4096
#define FEATC 32
#define PRES 256
#define NSAMP 92
#define STEPF ((2.7f - 1.0f) / 92.0f)
#define FOVF 0.8575560548920328f

#define TPB 256               // 4 waves; 1 ray per wave
#define HPAD 72               // hbuf row stride (bf16), 144B: mult of 16 -> aligned b128

// -------- transpose planes (v,pl,c,y,x) -> (v,pl,y,x,c) --------
__global__ __launch_bounds__(PRES) void transpose_planes(
    const float* __restrict__ in, float* __restrict__ out) {
  int b  = blockIdx.x;          // vp*256 + y
  int vp = b >> 8;
  int y  = b & 255;
  int x  = threadIdx.x;
  const float* src = in + (size_t)vp * FEATC * PRES * PRES + (size_t)y * PRES + x;
  float* dst = out + (((size_t)vp * PRES + y) * PRES + x) * FEATC;
  float v[FEATC];
#pragma unroll
  for (int c = 0; c < FEATC; ++c) v[c] = src[(size_t)c * PRES * PRES];
#pragma unroll
  for (int q = 0; q < FEATC / 4; ++q) {
    float4 t = make_float4(v[q * 4 + 0], v[q * 4 + 1], v[q * 4 + 2], v[q * 4 + 3]);
    *reinterpret_cast<float4*>(dst + q * 4) = t;
  }
}

__device__ __forceinline__ unsigned short f2bf(float x) {
  unsigned int u = __float_as_uint(x);
  u += 0x7fffu + ((u >> 16) & 1u);
  return (unsigned short)(u >> 16);
}
__device__ __forceinline__ f32x2 mk2(float a, float b) { f32x2 r; r[0] = a; r[1] = b; return r; }

// wave-internal LDS fence: DS ops within a wave complete in order; lgkmcnt(0)
// guarantees prior writes landed, sched_barrier(0) stops compiler motion.
__device__ __forceinline__ void wfence() {
  asm volatile("s_waitcnt lgkmcnt(0)" ::: "memory");
  __builtin_amdgcn_sched_barrier(0);
}

// -------- fully waveized fused MFMA render: 1 ray per wave, ZERO block barriers --------
// Each wave owns a private hbuf slice [32][HPAD] and processes its ray's 92
// samples in 3 iters of 32 rows. All producer->consumer deps are wave-internal.
// __launch_bounds__(256,2): VGPR cap 256. NOTE: (.,4) forces a 64-VGPR cap on
// this toolchain -> ~1GB scratch spill (rounds 4-5). Do not use.
template <int TR>
__global__ __launch_bounds__(TPB, 2) void render_wave(
    const float* __restrict__ c2w, const float* __restrict__ planes,
    const float* __restrict__ background, const float* __restrict__ t_jitter,
    const float* __restrict__ W1, const float* __restrict__ b1,
    const float* __restrict__ W2, const float* __restrict__ b2,
    const float* __restrict__ Wr1, const float* __restrict__ br1,
    const float* __restrict__ Wr2, const float* __restrict__ br2,
    float* __restrict__ out) {
  __shared__ __bf16 hbufA[4][32][HPAD];   // per-wave: feat -> h -> colorA -> hr
  __shared__ float alphaA[4][96];         // per-wave raw sigma logits
  __shared__ float rgbA[4][96 * 3];       // per-wave raw rgb logits

  const int tid = threadIdx.x;
  const int w = tid >> 6;        // wave 0..3
  const int lane = tid & 63;
  const int lr = lane & 15;
  const int lg = lane >> 4;

  __bf16 (*hbuf)[HPAD] = hbufA[w];
  float* alphaL = alphaA[w];
  float* rgbL = rgbA[w];

  // ---- weight fragments: direct per-lane global loads (L1-broadcast) ----
  // B-frag layout (16x16x32): col n = lane&15, k = (lane>>4)*8 + i
  bf16x8 fW1[3][4], fW2[2], fR1[4], fR2[2];
#pragma unroll
  for (int ks = 0; ks < 3; ++ks)
#pragma unroll
    for (int nt = 0; nt < 4; ++nt) {
      union { unsigned short u[8]; bf16x8 b; } t;
#pragma unroll
      for (int i = 0; i < 8; ++i)
        t.u[i] = f2bf(W1[(ks * 32 + lg * 8 + i) * 64 + nt * 16 + lr]);
      fW1[ks][nt] = t.b;
    }
#pragma unroll
  for (int ks = 0; ks < 2; ++ks) {
    union { unsigned short u[8]; bf16x8 b; } t;
#pragma unroll
    for (int i = 0; i < 8; ++i)
      t.u[i] = f2bf(W2[(ks * 32 + lg * 8 + i) * 16 + lr]);
    fW2[ks] = t.b;
  }
#pragma unroll
  for (int nt = 0; nt < 4; ++nt) {
    union { unsigned short u[8]; bf16x8 b; } t;
#pragma unroll
    for (int i = 0; i < 8; ++i) {
      const int k = lg * 8 + i;
      t.u[i] = (k < 18) ? f2bf(Wr1[k * 64 + nt * 16 + lr]) : (unsigned short)0;
    }
    fR1[nt] = t.b;
  }
#pragma unroll
  for (int ks = 0; ks < 2; ++ks) {
    union { unsigned short u[8]; bf16x8 b; } t;
#pragma unroll
    for (int i = 0; i < 8; ++i)
      t.u[i] = (lr < 3) ? f2bf(Wr2[(ks * 32 + lg * 8 + i) * 3 + lr]) : (unsigned short)0;
    fR2[ks] = t.b;
  }
  float b1v[4], br1v[4];
#pragma unroll
  for (int nt = 0; nt < 4; ++nt) { b1v[nt] = b1[nt * 16 + lr]; br1v[nt] = br1[nt * 16 + lr]; }
  const float b2v = b2[lr];
  const float br2v = (lr < 3) ? br2[lr] : 0.f;

  // ---- ray setup (wave-uniform: 1 ray per wave) ----
  const int ray = blockIdx.x * 4 + w;
  const int view = ray >> 12;
  const int p = ray & 4095;
  const float foc = 0.5f * (float)RESN / tanf(FOVF * 0.5f);
  const float dxn = ((float)(p & 63) + 0.5f - 32.f) / foc;
  const float dyn = ((float)(p >> 6) + 0.5f - 32.f) / foc;
  const float* M = c2w + view * 16;
  const float rdx = M[0] * dxn + M[1] * dyn + M[2];
  const float rdy = M[4] * dxn + M[5] * dyn + M[6];
  const float rdz = M[8] * dxn + M[9] * dyn + M[10];
  const float rox = M[3] + 0.5f, roy = M[7] + 0.5f, roz = M[11] + 0.5f;
  const unsigned int dirxy = (unsigned int)f2bf(rdx) | ((unsigned int)f2bf(rdy) << 16);
  const unsigned short dirz = f2bf(rdz);

  const int mc = lane >> 1;      // row 0..31 (2 lanes per sample row)
  const int half = lane & 1;

  for (int iter = 0; iter < 3; ++iter) {
    const int s = iter * 32 + mc;              // rows 92..95 compute garbage (unused)
    const int sj = (s < NSAMP) ? s : (NSAMP - 1);
    const float jit = t_jitter[(size_t)ray * NSAMP + sj];
    const float t = 1.0f + ((float)s + jit) * STEPF + STEPF * 0.5f;
    const float px = fminf(fmaxf(rox + rdx * t, 0.f), 1.f);
    const float py = fminf(fmaxf(roy + rdy * t, 0.f), 1.f);
    const float pz = fminf(fmaxf(roz + rdz * t, 0.f), 1.f);

    // ---- all 3 planes' bilinear features -> regs (one gather latency/iter) ----
    bf16x8 fv[3][2];
#pragma unroll
    for (int pl = 0; pl < 3; ++pl) {
      const float uu = (pl == 2) ? py : px;
      const float vv = (pl == 0) ? py : pz;
      const float xf = uu * 255.f, yf = vv * 255.f;
      const float x0f = floorf(xf), y0f = floorf(yf);
      const float wx = xf - x0f, wy = yf - y0f;
      const int x0 = (int)x0f, y0 = (int)y0f;
      const int x1 = min(x0 + 1, 255), y1 = min(y0 + 1, 255);
      const float w00 = (1.f - wx) * (1.f - wy), w01 = wx * (1.f - wy);
      const float w10 = (1.f - wx) * wy, w11 = wx * wy;
      bf16x8 v0, v1;
      if (TR) {
        const float* pb = planes + (size_t)(view * 3 + pl) * (PRES * PRES * FEATC) + half * 16;
        const float* p00 = pb + (size_t)(y0 * 256 + x0) * 32;
        const float* p01 = pb + (size_t)(y0 * 256 + x1) * 32;
        const float* p10 = pb + (size_t)(y1 * 256 + x0) * 32;
        const float* p11 = pb + (size_t)(y1 * 256 + x1) * 32;
        f32x2 fp[8];
#pragma unroll
        for (int q = 0; q < 4; ++q) {
          const float4 a = *(const float4*)(p00 + q * 4);
          const float4 b = *(const float4*)(p01 + q * 4);
          const float4 c = *(const float4*)(p10 + q * 4);
          const float4 d = *(const float4*)(p11 + q * 4);
          fp[q * 2 + 0] = mk2(a.x, a.y) * w00 + mk2(b.x, b.y) * w01 +
                          mk2(c.x, c.y) * w10 + mk2(d.x, d.y) * w11;
          fp[q * 2 + 1] = mk2(a.z, a.w) * w00 + mk2(b.z, b.w) * w01 +
                          mk2(c.z, c.w) * w10 + mk2(d.z, d.w) * w11;
        }
#pragma unroll
        for (int i = 0; i < 4; ++i) {
          v0[2 * i] = (__bf16)fp[i][0];       v0[2 * i + 1] = (__bf16)fp[i][1];
          v1[2 * i] = (__bf16)fp[4 + i][0];   v1[2 * i + 1] = (__bf16)fp[4 + i][1];
        }
      } else {
        const float* pb = planes + (size_t)(view * 3 + pl) * (FEATC * PRES * PRES) +
                          (size_t)(half * 16) * (PRES * PRES);
        const int o00 = y0 * 256 + x0, o01 = y0 * 256 + x1;
        const int o10 = y1 * 256 + x0, o11 = y1 * 256 + x1;
        float f[16];
#pragma unroll
        for (int cc = 0; cc < 16; ++cc) {
          const float* pc = pb + (size_t)cc * (PRES * PRES);
          f[cc] = pc[o00] * w00 + pc[o01] * w01 + pc[o10] * w10 + pc[o11] * w11;
        }
#pragma unroll
        for (int i = 0; i < 8; ++i) { v0[i] = (__bf16)f[i]; v1[i] = (__bf16)f[8 + i]; }
      }
      fv[pl][0] = v0; fv[pl][1] = v1;
    }

    // ---- GEMM1: feat[32x96] @ W1, K streamed per plane (wave-local) ----
    f32x4 acc1[2][4] = {};
#pragma unroll
    for (int pl = 0; pl < 3; ++pl) {
      wfence();   // WAR: prior hbuf reads (prev plane A / prev iter GEMM4) retired
      *(bf16x8*)&hbuf[mc][half * 16] = fv[pl][0];
      *(bf16x8*)&hbuf[mc][half * 16 + 8] = fv[pl][1];
      wfence();   // RAW: feat visible to all lanes of this wave
#pragma unroll
      for (int mt = 0; mt < 2; ++mt) {
        const bf16x8 a = *(const bf16x8*)&hbuf[mt * 16 + lr][lg * 8];
#pragma unroll
        for (int nt = 0; nt < 4; ++nt)
          acc1[mt][nt] = __builtin_amdgcn_mfma_f32_16x16x32_bf16(a, fW1[pl][nt], acc1[mt][nt], 0, 0, 0);
      }
    }
    wfence();
    // h = relu(acc1 + b1) -> hbuf cols 0..63
#pragma unroll
    for (int mt = 0; mt < 2; ++mt)
#pragma unroll
      for (int nt = 0; nt < 4; ++nt)
#pragma unroll
        for (int r = 0; r < 4; ++r) {
          const int m = mt * 16 + lg * 4 + r;
          hbuf[m][nt * 16 + lr] = (__bf16)fmaxf(acc1[mt][nt][r] + b1v[nt], 0.f);
        }
    wfence();
    // ---- GEMM2: h @ W2 (64->16) ----
    f32x4 acc2[2] = {};
#pragma unroll
    for (int mt = 0; mt < 2; ++mt) {
      const bf16x8 a0 = *(const bf16x8*)&hbuf[mt * 16 + lr][lg * 8];
      const bf16x8 a1 = *(const bf16x8*)&hbuf[mt * 16 + lr][32 + lg * 8];
      acc2[mt] = __builtin_amdgcn_mfma_f32_16x16x32_bf16(a0, fW2[0], acc2[mt], 0, 0, 0);
      acc2[mt] = __builtin_amdgcn_mfma_f32_16x16x32_bf16(a1, fW2[1], acc2[mt], 0, 0, 0);
    }
    wfence();
    // epilogue: raw sigma -> alphaL; dir -> cols 0..2; geo -> cols 3..17
#pragma unroll
    for (int mt = 0; mt < 2; ++mt)
#pragma unroll
      for (int r = 0; r < 4; ++r) {
        const int m = mt * 16 + lg * 4 + r;
        const int s2 = iter * 32 + m;
        const float val = acc2[mt][r] + b2v;
        if (lr == 0) {
          alphaL[s2] = val;
          *(unsigned int*)&hbuf[m][0] = dirxy;
          *(unsigned short*)&hbuf[m][2] = dirz;
        } else {
          hbuf[m][2 + lr] = (__bf16)val;   // geo i=lr-1 -> col 3+(lr-1)
        }
      }
    wfence();
    // ---- GEMM3: colorA[32x32] @ Wr1pad (cols 18..31 stale x zero weights) ----
    f32x4 acc3[2][4] = {};
#pragma unroll
    for (int mt = 0; mt < 2; ++mt) {
      const bf16x8 a = *(const bf16x8*)&hbuf[mt * 16 + lr][lg * 8];
#pragma unroll
      for (int nt = 0; nt < 4; ++nt)
        acc3[mt][nt] = __builtin_amdgcn_mfma_f32_16x16x32_bf16(a, fR1[nt], acc3[mt][nt], 0, 0, 0);
    }
    wfence();
    // hr = relu(acc3 + br1) -> hbuf cols 0..63
#pragma unroll
    for (int mt = 0; mt < 2; ++mt)
#pragma unroll
      for (int nt = 0; nt < 4; ++nt)
#pragma unroll
        for (int r = 0; r < 4; ++r) {
          const int m = mt * 16 + lg * 4 + r;
          hbuf[m][nt * 16 + lr] = (__bf16)fmaxf(acc3[mt][nt][r] + br1v[nt], 0.f);
        }
    wfence();
    // ---- GEMM4: hr @ Wr2pad -> raw rgb logits ----
    f32x4 acc4[2] = {};
#pragma unroll
    for (int mt = 0; mt < 2; ++mt) {
      const bf16x8 a0 = *(const bf16x8*)&hbuf[mt * 16 + lr][lg * 8];
      const bf16x8 a1 = *(const bf16x8*)&hbuf[mt * 16 + lr][32 + lg * 8];
      acc4[mt] = __builtin_amdgcn_mfma_f32_16x16x32_bf16(a0, fR2[0], acc4[mt], 0, 0, 0);
      acc4[mt] = __builtin_amdgcn_mfma_f32_16x16x32_bf16(a1, fR2[1], acc4[mt], 0, 0, 0);
    }
#pragma unroll
    for (int mt = 0; mt < 2; ++mt)
#pragma unroll
      for (int r = 0; r < 4; ++r) {
        const int m = mt * 16 + lg * 4 + r;
        const int s2 = iter * 32 + m;
        if (lr < 3) rgbL[s2 * 3 + lr] = acc4[mt][r] + br2v;
      }
  }
  wfence();

  // ---- per-wave composite with inline activations ----
  {
    // phase A: samples 0..63
    const float o0 = alphaL[lane];
    const float sp = fmaxf(o0, 0.f) + log1pf(__expf(-fabsf(o0)));
    const float a = 1.f - __expf(-sp * STEPF);
    float r0 = rgbL[lane * 3 + 0], r1 = rgbL[lane * 3 + 1], r2 = rgbL[lane * 3 + 2];
    r0 = 1.f / (1.f + __expf(-r0));
    r1 = 1.f / (1.f + __expf(-r1));
    r2 = 1.f / (1.f + __expf(-r2));
    float q = 1.f - a + 1e-10f;
#pragma unroll
    for (int d = 1; d < 64; d <<= 1) { const float t = __shfl_up(q, d); if (lane >= d) q *= t; }
    float T = __shfl_up(q, 1);
    if (lane == 0) T = 1.f;
    const float wgt = T * a;
    float cr = wgt * r0, cg = wgt * r1, cb = wgt * r2, accA = wgt;
    const float Ttot = __shfl(q, 63);
    // phase B: samples 64..91 on lanes 0..27
    float a2 = 0.f, s0 = 0.f, s1 = 0.f, s2c = 0.f;
    if (lane < 28) {
      const int i2 = 64 + lane;
      const float o0b = alphaL[i2];
      const float spb = fmaxf(o0b, 0.f) + log1pf(__expf(-fabsf(o0b)));
      a2 = 1.f - __expf(-spb * STEPF);
      s0 = 1.f / (1.f + __expf(-rgbL[i2 * 3 + 0]));
      s1 = 1.f / (1.f + __expf(-rgbL[i2 * 3 + 1]));
      s2c = 1.f / (1.f + __expf(-rgbL[i2 * 3 + 2]));
    }
    float q2 = 1.f - a2 + 1e-10f;
#pragma unroll
    for (int d = 1; d < 64; d <<= 1) { const float t = __shfl_up(q2, d); if (lane >= d) q2 *= t; }
    float T2 = __shfl_up(q2, 1);
    if (lane == 0) T2 = 1.f;
    T2 *= Ttot;
    if (lane < 28) {
      const float w2 = T2 * a2;
      cr += w2 * s0; cg += w2 * s1; cb += w2 * s2c;
      accA += w2;
    }
#pragma unroll
    for (int d = 32; d; d >>= 1) {
      cr += __shfl_xor(cr, d); cg += __shfl_xor(cg, d);
      cb += __shfl_xor(cb, d); accA += __shfl_xor(accA, d);
    }
    if (lane == 0) {
      const float* bg = background + view * 3;
      float* po = out + (size_t)ray * 3;
      po[0] = cr + (1.f - accA) * bg[0];
      po[1] = cg + (1.f - accA) * bg[1];
      po[2] = cb + (1.f - accA) * bg[2];
    }
  }
}

extern "C" void kernel_launch(void* const* d_in, const int* in_sizes, int n_in,
                              void* d_out, int out_size, void* d_ws, size_t ws_size,
                              hipStream_t stream) {
  const float* c2w        = (const float*)d_in[0];
  const float* planes     = (const float*)d_in[1];
  const float* background = (const float*)d_in[2];
  const float* t_jitter   = (const float*)d_in[3];
  const float* W1  = (const float*)d_in[4];
  const float* b1  = (const float*)d_in[5];
  const float* W2  = (const float*)d_in[6];
  const float* b2  = (const float*)d_in[7];
  const float* Wr1 = (const float*)d_in[8];
  const float* br1 = (const float*)d_in[9];
  const float* Wr2 = (const float*)d_in[10];
  const float* br2 = (const float*)d_in[11];
  float* out = (float*)d_out;

  const int n_blocks = NVIEWS * PP / 4;    // 4096 blocks, 1 ray per wave
  const size_t tr_bytes = (size_t)NVIEWS * 3 * PRES * PRES * FEATC * sizeof(float);

  if (ws_size >= tr_bytes) {
    float* tp = (float*)d_ws;
    transpose_planes<<<NVIEWS * 3 * PRES, PRES, 0, stream>>>(planes, tp);
    render_wave<1><<<n_blocks, TPB, 0, stream>>>(
        c2w, tp, background, t_jitter, W1, b1, W2, b2, Wr1, br1, Wr2, br2, out);
  } else {
    render_wave<0><<<n_blocks, TPB, 0, stream>>>(
        c2w, planes, background, t_jitter, W1, b1, W2, b2, Wr1, br1, Wr2, br2, out);
  }
}

// Round 8
// 229.431 us; speedup vs baseline: 1.0286x; 1.0286x over previous
//
#include <hip/hip_runtime.h>
#include <math.h>

typedef __bf16 bf16x8 __attribute__((ext_vector_type(8)));
typedef float f32x4 __attribute__((ext_vector_type(4)));
typedef float f32x2 __attribute__((ext_vector_type(2)));

#define NVIEWS 4
#define RESN 64
#define PP 4096
#define FEATC 32
#define PRES 256
#define NSAMP 92
#define STEPF ((2.7f - 1.0f) / 92.0f)
#define FOVF 0.8575560548920328f

#define TPB 256               // 4 waves; 1 ray per wave
#define FPAD 104              // feat row stride (96 cols + pad), 208B mult of 16
#define HPAD2 72              // h/hr row stride, 144B mult of 16

// -------- transpose planes (v,pl,c,y,x) -> (v,pl,y,x,c) --------
__global__ __launch_bounds__(PRES) void transpose_planes(
    const float* __restrict__ in, float* __restrict__ out) {
  int b  = blockIdx.x;          // vp*256 + y
  int vp = b >> 8;
  int y  = b & 255;
  int x  = threadIdx.x;
  const float* src = in + (size_t)vp * FEATC * PRES * PRES + (size_t)y * PRES + x;
  float* dst = out + (((size_t)vp * PRES + y) * PRES + x) * FEATC;
  float v[FEATC];
#pragma unroll
  for (int c = 0; c < FEATC; ++c) v[c] = src[(size_t)c * PRES * PRES];
#pragma unroll
  for (int q = 0; q < FEATC / 4; ++q) {
    float4 t = make_float4(v[q * 4 + 0], v[q * 4 + 1], v[q * 4 + 2], v[q * 4 + 3]);
    *reinterpret_cast<float4*>(dst + q * 4) = t;
  }
}

__device__ __forceinline__ unsigned short f2bf(float x) {
  unsigned int u = __float_as_uint(x);
  u += 0x7fffu + ((u >> 16) & 1u);
  return (unsigned short)(u >> 16);
}
__device__ __forceinline__ f32x2 mk2(float a, float b) { f32x2 r; r[0] = a; r[1] = b; return r; }

// wave-internal LDS fence: DS ops within a wave complete in order; lgkmcnt(0)
// guarantees prior ops landed, sched_barrier(0) stops compiler motion.
__device__ __forceinline__ void wfence() {
  asm volatile("s_waitcnt lgkmcnt(0)" ::: "memory");
  __builtin_amdgcn_sched_barrier(0);
}

// -------- fully waveized fused MFMA render: 1 ray/wave, zero block barriers --------
// vs r7: nt-outer GEMM1/GEMM3 (only 8 acc regs live, not 32) + all-3-planes feat
// staged at once -> per-wave footprint fits 3 waves/SIMD; LDS 50KB/block ->
// 3 blocks/CU = 12 waves/CU (was ~8). 5 fences/iter (was 12).
// NOTE: __launch_bounds__(.,4) forces a 64-VGPR cap -> ~1GB spill (r4-r5). Use (.,2).
template <int TR>
__global__ __launch_bounds__(TPB, 2) void render_wave(
    const float* __restrict__ c2w, const float* __restrict__ planes,
    const float* __restrict__ background, const float* __restrict__ t_jitter,
    const float* __restrict__ W1, const float* __restrict__ b1,
    const float* __restrict__ W2, const float* __restrict__ b2,
    const float* __restrict__ Wr1, const float* __restrict__ br1,
    const float* __restrict__ Wr2, const float* __restrict__ br2,
    float* __restrict__ out) {
  __shared__ __bf16 featA[4][32][FPAD];   // per-wave: feat(0..95) -> colorA(0..31)
  __shared__ __bf16 hA[4][32][HPAD2];     // per-wave: h(0..63) -> hr(0..63)
  __shared__ float alphaA[4][96];         // per-wave raw sigma logits
  __shared__ float rgbA[4][96 * 3];       // per-wave raw rgb logits

  const int tid = threadIdx.x;
  const int w = tid >> 6;        // wave 0..3
  const int lane = tid & 63;
  const int lr = lane & 15;
  const int lg = lane >> 4;

  __bf16 (*feat)[FPAD] = featA[w];
  __bf16 (*hB)[HPAD2] = hA[w];
  float* alphaL = alphaA[w];
  float* rgbL = rgbA[w];

  // ---- weight fragments: direct per-lane global loads (L1-broadcast) ----
  // B-frag layout (16x16x32): col n = lane&15, k = (lane>>4)*8 + i
  bf16x8 fW1[3][4], fW2[2], fR1[4], fR2[2];
#pragma unroll
  for (int ks = 0; ks < 3; ++ks)
#pragma unroll
    for (int nt = 0; nt < 4; ++nt) {
      union { unsigned short u[8]; bf16x8 b; } t;
#pragma unroll
      for (int i = 0; i < 8; ++i)
        t.u[i] = f2bf(W1[(ks * 32 + lg * 8 + i) * 64 + nt * 16 + lr]);
      fW1[ks][nt] = t.b;
    }
#pragma unroll
  for (int ks = 0; ks < 2; ++ks) {
    union { unsigned short u[8]; bf16x8 b; } t;
#pragma unroll
    for (int i = 0; i < 8; ++i)
      t.u[i] = f2bf(W2[(ks * 32 + lg * 8 + i) * 16 + lr]);
    fW2[ks] = t.b;
  }
#pragma unroll
  for (int nt = 0; nt < 4; ++nt) {
    union { unsigned short u[8]; bf16x8 b; } t;
#pragma unroll
    for (int i = 0; i < 8; ++i) {
      const int k = lg * 8 + i;
      t.u[i] = (k < 18) ? f2bf(Wr1[k * 64 + nt * 16 + lr]) : (unsigned short)0;
    }
    fR1[nt] = t.b;
  }
#pragma unroll
  for (int ks = 0; ks < 2; ++ks) {
    union { unsigned short u[8]; bf16x8 b; } t;
#pragma unroll
    for (int i = 0; i < 8; ++i)
      t.u[i] = (lr < 3) ? f2bf(Wr2[(ks * 32 + lg * 8 + i) * 3 + lr]) : (unsigned short)0;
    fR2[ks] = t.b;
  }
  float b1v[4], br1v[4];
#pragma unroll
  for (int nt = 0; nt < 4; ++nt) { b1v[nt] = b1[nt * 16 + lr]; br1v[nt] = br1[nt * 16 + lr]; }
  const float b2v = b2[lr];
  const float br2v = (lr < 3) ? br2[lr] : 0.f;

  // ---- ray setup (wave-uniform: 1 ray per wave) ----
  const int ray = blockIdx.x * 4 + w;
  const int view = ray >> 12;
  const int p = ray & 4095;
  const float foc = 0.5f * (float)RESN / tanf(FOVF * 0.5f);
  const float dxn = ((float)(p & 63) + 0.5f - 32.f) / foc;
  const float dyn = ((float)(p >> 6) + 0.5f - 32.f) / foc;
  const float* M = c2w + view * 16;
  const float rdx = M[0] * dxn + M[1] * dyn + M[2];
  const float rdy = M[4] * dxn + M[5] * dyn + M[6];
  const float rdz = M[8] * dxn + M[9] * dyn + M[10];
  const float rox = M[3] + 0.5f, roy = M[7] + 0.5f, roz = M[11] + 0.5f;
  const unsigned int dirxy = (unsigned int)f2bf(rdx) | ((unsigned int)f2bf(rdy) << 16);
  const unsigned short dirz = f2bf(rdz);

  const int mc = lane >> 1;      // row 0..31 (2 lanes per sample row)
  const int half = lane & 1;

  for (int iter = 0; iter < 3; ++iter) {
    const int s = iter * 32 + mc;              // rows 92..95 compute garbage (unused)
    const int sj = (s < NSAMP) ? s : (NSAMP - 1);
    const float jit = t_jitter[(size_t)ray * NSAMP + sj];
    const float t = 1.0f + ((float)s + jit) * STEPF + STEPF * 0.5f;
    const float px = fminf(fmaxf(rox + rdx * t, 0.f), 1.f);
    const float py = fminf(fmaxf(roy + rdy * t, 0.f), 1.f);
    const float pz = fminf(fmaxf(roz + rdz * t, 0.f), 1.f);

    wfence();   // WAR: prev iter's GEMM3 feat-reads + GEMM4 hB-reads retired
    // ---- stage all 3 planes' bilinear features -> feat cols 0..95 ----
#pragma unroll
    for (int pl = 0; pl < 3; ++pl) {
      const float uu = (pl == 2) ? py : px;
      const float vv = (pl == 0) ? py : pz;
      const float xf = uu * 255.f, yf = vv * 255.f;
      const float x0f = floorf(xf), y0f = floorf(yf);
      const float wx = xf - x0f, wy = yf - y0f;
      const int x0 = (int)x0f, y0 = (int)y0f;
      const int x1 = min(x0 + 1, 255), y1 = min(y0 + 1, 255);
      const float w00 = (1.f - wx) * (1.f - wy), w01 = wx * (1.f - wy);
      const float w10 = (1.f - wx) * wy, w11 = wx * wy;
      bf16x8 v0, v1;
      if (TR) {
        const float* pb = planes + (size_t)(view * 3 + pl) * (PRES * PRES * FEATC) + half * 16;
        const float* p00 = pb + (size_t)(y0 * 256 + x0) * 32;
        const float* p01 = pb + (size_t)(y0 * 256 + x1) * 32;
        const float* p10 = pb + (size_t)(y1 * 256 + x0) * 32;
        const float* p11 = pb + (size_t)(y1 * 256 + x1) * 32;
        f32x2 fp[8];
#pragma unroll
        for (int q = 0; q < 4; ++q) {
          const float4 a = *(const float4*)(p00 + q * 4);
          const float4 b = *(const float4*)(p01 + q * 4);
          const float4 c = *(const float4*)(p10 + q * 4);
          const float4 d = *(const float4*)(p11 + q * 4);
          fp[q * 2 + 0] = mk2(a.x, a.y) * w00 + mk2(b.x, b.y) * w01 +
                          mk2(c.x, c.y) * w10 + mk2(d.x, d.y) * w11;
          fp[q * 2 + 1] = mk2(a.z, a.w) * w00 + mk2(b.z, b.w) * w01 +
                          mk2(c.z, c.w) * w10 + mk2(d.z, d.w) * w11;
        }
#pragma unroll
        for (int i = 0; i < 4; ++i) {
          v0[2 * i] = (__bf16)fp[i][0];       v0[2 * i + 1] = (__bf16)fp[i][1];
          v1[2 * i] = (__bf16)fp[4 + i][0];   v1[2 * i + 1] = (__bf16)fp[4 + i][1];
        }
      } else {
        const float* pb = planes + (size_t)(view * 3 + pl) * (FEATC * PRES * PRES) +
                          (size_t)(half * 16) * (PRES * PRES);
        const int o00 = y0 * 256 + x0, o01 = y0 * 256 + x1;
        const int o10 = y1 * 256 + x0, o11 = y1 * 256 + x1;
        float f[16];
#pragma unroll
        for (int cc = 0; cc < 16; ++cc) {
          const float* pc = pb + (size_t)cc * (PRES * PRES);
          f[cc] = pc[o00] * w00 + pc[o01] * w01 + pc[o10] * w10 + pc[o11] * w11;
        }
#pragma unroll
        for (int i = 0; i < 8; ++i) { v0[i] = (__bf16)f[i]; v1[i] = (__bf16)f[8 + i]; }
      }
      *(bf16x8*)&feat[mc][pl * 32 + half * 16] = v0;
      *(bf16x8*)&feat[mc][pl * 32 + half * 16 + 8] = v1;
    }
    wfence();   // RAW: feat visible to all lanes of this wave

    // ---- GEMM1 (nt-outer, 8 acc regs live): h = relu(feat @ W1 + b1) ----
#pragma unroll
    for (int nt = 0; nt < 4; ++nt) {
      f32x4 acc[2] = {};
#pragma unroll
      for (int pl = 0; pl < 3; ++pl)
#pragma unroll
        for (int mt = 0; mt < 2; ++mt) {
          const bf16x8 a = *(const bf16x8*)&feat[mt * 16 + lr][pl * 32 + lg * 8];
          acc[mt] = __builtin_amdgcn_mfma_f32_16x16x32_bf16(a, fW1[pl][nt], acc[mt], 0, 0, 0);
        }
#pragma unroll
      for (int mt = 0; mt < 2; ++mt)
#pragma unroll
        for (int r = 0; r < 4; ++r)
          hB[mt * 16 + lg * 4 + r][nt * 16 + lr] = (__bf16)fmaxf(acc[mt][r] + b1v[nt], 0.f);
    }
    wfence();   // RAW: h visible

    // ---- GEMM2: h @ W2 (64->16) ----
    f32x4 acc2[2] = {};
#pragma unroll
    for (int mt = 0; mt < 2; ++mt) {
      const bf16x8 a0 = *(const bf16x8*)&hB[mt * 16 + lr][lg * 8];
      const bf16x8 a1 = *(const bf16x8*)&hB[mt * 16 + lr][32 + lg * 8];
      acc2[mt] = __builtin_amdgcn_mfma_f32_16x16x32_bf16(a0, fW2[0], acc2[mt], 0, 0, 0);
      acc2[mt] = __builtin_amdgcn_mfma_f32_16x16x32_bf16(a1, fW2[1], acc2[mt], 0, 0, 0);
    }
    // epilogue: raw sigma -> alphaL; dir -> feat cols 0..2; geo -> feat cols 3..17
    // (feat region dead after GEMM1; fR1 rows 18..31 are zero so stale cols OK)
#pragma unroll
    for (int mt = 0; mt < 2; ++mt)
#pragma unroll
      for (int r = 0; r < 4; ++r) {
        const int m = mt * 16 + lg * 4 + r;
        const int s2 = iter * 32 + m;
        const float val = acc2[mt][r] + b2v;
        if (lr == 0) {
          alphaL[s2] = val;
          *(unsigned int*)&feat[m][0] = dirxy;
          *(unsigned short*)&feat[m][2] = dirz;
        } else {
          feat[m][2 + lr] = (__bf16)val;   // geo i=lr-1 -> col 3+(lr-1)
        }
      }
    wfence();   // RAW: colorA visible

    // ---- GEMM3 (nt-outer): hr = relu(colorA @ Wr1pad + br1) ----
#pragma unroll
    for (int nt = 0; nt < 4; ++nt) {
      f32x4 acc[2] = {};
#pragma unroll
      for (int mt = 0; mt < 2; ++mt) {
        const bf16x8 a = *(const bf16x8*)&feat[mt * 16 + lr][lg * 8];
        acc[mt] = __builtin_amdgcn_mfma_f32_16x16x32_bf16(a, fR1[nt], acc[mt], 0, 0, 0);
      }
#pragma unroll
      for (int mt = 0; mt < 2; ++mt)
#pragma unroll
        for (int r = 0; r < 4; ++r)
          hB[mt * 16 + lg * 4 + r][nt * 16 + lr] = (__bf16)fmaxf(acc[mt][r] + br1v[nt], 0.f);
    }
    wfence();   // RAW: hr visible

    // ---- GEMM4: hr @ Wr2pad -> raw rgb logits ----
    f32x4 acc4[2] = {};
#pragma unroll
    for (int mt = 0; mt < 2; ++mt) {
      const bf16x8 a0 = *(const bf16x8*)&hB[mt * 16 + lr][lg * 8];
      const bf16x8 a1 = *(const bf16x8*)&hB[mt * 16 + lr][32 + lg * 8];
      acc4[mt] = __builtin_amdgcn_mfma_f32_16x16x32_bf16(a0, fR2[0], acc4[mt], 0, 0, 0);
      acc4[mt] = __builtin_amdgcn_mfma_f32_16x16x32_bf16(a1, fR2[1], acc4[mt], 0, 0, 0);
    }
#pragma unroll
    for (int mt = 0; mt < 2; ++mt)
#pragma unroll
      for (int r = 0; r < 4; ++r) {
        const int m = mt * 16 + lg * 4 + r;
        const int s2 = iter * 32 + m;
        if (lr < 3) rgbL[s2 * 3 + lr] = acc4[mt][r] + br2v;
      }
  }
  wfence();

  // ---- per-wave composite with inline activations ----
  {
    // phase A: samples 0..63
    const float o0 = alphaL[lane];
    const float sp = fmaxf(o0, 0.f) + log1pf(__expf(-fabsf(o0)));
    const float a = 1.f - __expf(-sp * STEPF);
    float r0 = rgbL[lane * 3 + 0], r1 = rgbL[lane * 3 + 1], r2 = rgbL[lane * 3 + 2];
    r0 = 1.f / (1.f + __expf(-r0));
    r1 = 1.f / (1.f + __expf(-r1));
    r2 = 1.f / (1.f + __expf(-r2));
    float q = 1.f - a + 1e-10f;
#pragma unroll
    for (int d = 1; d < 64; d <<= 1) { const float t = __shfl_up(q, d); if (lane >= d) q *= t; }
    float T = __shfl_up(q, 1);
    if (lane == 0) T = 1.f;
    const float wgt = T * a;
    float cr = wgt * r0, cg = wgt * r1, cb = wgt * r2, accA = wgt;
    const float Ttot = __shfl(q, 63);
    // phase B: samples 64..91 on lanes 0..27
    float a2 = 0.f, s0 = 0.f, s1 = 0.f, s2c = 0.f;
    if (lane < 28) {
      const int i2 = 64 + lane;
      const float o0b = alphaL[i2];
      const float spb = fmaxf(o0b, 0.f) + log1pf(__expf(-fabsf(o0b)));
      a2 = 1.f - __expf(-spb * STEPF);
      s0 = 1.f / (1.f + __expf(-rgbL[i2 * 3 + 0]));
      s1 = 1.f / (1.f + __expf(-rgbL[i2 * 3 + 1]));
      s2c = 1.f / (1.f + __expf(-rgbL[i2 * 3 + 2]));
    }
    float q2 = 1.f - a2 + 1e-10f;
#pragma unroll
    for (int d = 1; d < 64; d <<= 1) { const float t = __shfl_up(q2, d); if (lane >= d) q2 *= t; }
    float T2 = __shfl_up(q2, 1);
    if (lane == 0) T2 = 1.f;
    T2 *= Ttot;
    if (lane < 28) {
      const float w2 = T2 * a2;
      cr += w2 * s0; cg += w2 * s1; cb += w2 * s2c;
      accA += w2;
    }
#pragma unroll
    for (int d = 32; d; d >>= 1) {
      cr += __shfl_xor(cr, d); cg += __shfl_xor(cg, d);
      cb += __shfl_xor(cb, d); accA += __shfl_xor(accA, d);
    }
    if (lane == 0) {
      const float* bg = background + view * 3;
      float* po = out + (size_t)ray * 3;
      po[0] = cr + (1.f - accA) * bg[0];
      po[1] = cg + (1.f - accA) * bg[1];
      po[2] = cb + (1.f - accA) * bg[2];
    }
  }
}

extern "C" void kernel_launch(void* const* d_in, const int* in_sizes, int n_in,
                              void* d_out, int out_size, void* d_ws, size_t ws_size,
                              hipStream_t stream) {
  const float* c2w        = (const float*)d_in[0];
  const float* planes     = (const float*)d_in[1];
  const float* background = (const float*)d_in[2];
  const float* t_jitter   = (const float*)d_in[3];
  const float* W1  = (const float*)d_in[4];
  const float* b1  = (const float*)d_in[5];
  const float* W2  = (const float*)d_in[6];
  const float* b2  = (const float*)d_in[7];
  const float* Wr1 = (const float*)d_in[8];
  const float* br1 = (const float*)d_in[9];
  const float* Wr2 = (const float*)d_in[10];
  const float* br2 = (const float*)d_in[11];
  float* out = (float*)d_out;

  const int n_blocks = NVIEWS * PP / 4;    // 4096 blocks, 1 ray per wave
  const size_t tr_bytes = (size_t)NVIEWS * 3 * PRES * PRES * FEATC * sizeof(float);

  if (ws_size >= tr_bytes) {
    float* tp = (float*)d_ws;
    transpose_planes<<<NVIEWS * 3 * PRES, PRES, 0, stream>>>(planes, tp);
    render_wave<1><<<n_blocks, TPB, 0, stream>>>(
        c2w, tp, background, t_jitter, W1, b1, W2, b2, Wr1, br1, Wr2, br2, out);
  } else {
    render_wave<0><<<n_blocks, TPB, 0, stream>>>(
        c2w, planes, background, t_jitter, W1, b1, W2, b2, Wr1, br1, Wr2, br2, out);
  }
}